// Round 12
// baseline (2752.174 us; speedup 1.0000x reference)
//
#include <hip/hip_runtime.h>

#define T_STEPS 1000
#define DT 0.1f
#define HIDDEN 128
#define N_AGENTS 1024

typedef float v2f __attribute__((ext_vector_type(2)));

// tanh(x) = 1 - 2/(exp(2x)+1); exact at +/-inf, ~1e-7 rel error.
__device__ __forceinline__ float tanh_fast(float x) {
    float e = __expf(2.0f * x);
    return 1.0f - 2.0f * __builtin_amdgcn_rcpf(e + 1.0f);
}

// Opaque 8B load (R13-R18 proven residency mechanism; serial per-load
// waitcnt -- the R21 batched variants are correctness-quarantined).
__device__ __forceinline__ v2f opaque_load8(const float* p) {
    v2f v;
    asm volatile("global_load_dwordx2 %0, %1, off\n\ts_waitcnt vmcnt(0)"
                 : "=v"(v)
                 : "v"((unsigned long long)(uintptr_t)p)
                 : "memory");
    return v;
}

// R31: AGPR weight residency. R30's merge was bit-exact but demanded ~490
// arch VGPRs against the 256 cap -> 240 regs spilled to scratch (FETCH
// 2.4GB, 1791us). Weights = exactly 256 floats of read-only data -> move
// to the 256-AGPR half of the unified file. Single-instruction reg-reg
// copies (write after proven load; read at use). Bit-exact by definition.
__device__ __forceinline__ void awrite(float& ax, float& ay, v2f v) {
    asm("v_accvgpr_write_b32 %0, %2\n\tv_accvgpr_write_b32 %1, %3"
        : "=a"(ax), "=a"(ay) : "v"(v.x), "v"(v.y));
}
__device__ __forceinline__ v2f aread(const float& ax, const float& ay) {
    float rx, ry;
    asm("v_accvgpr_read_b32 %0, %2\n\tv_accvgpr_read_b32 %1, %3"
        : "=v"(rx), "=v"(ry) : "a"(ax), "a"(ay));
    return (v2f){rx, ry};
}

__device__ __forceinline__ float uniformf(float v) {
    return __builtin_bit_cast(float,
        __builtin_amdgcn_readfirstlane(__builtin_bit_cast(int, v)));
}

// R25 fused dual-DPP reduction; non-volatile (R29-proven bit-safe): in the
// single-wave regime the scheduler must be free to interleave independent
// tap work into the reduction's wait slots.
__device__ __forceinline__ void wave_sum2_dpp(float& a, float& b) {
    asm(
        "s_nop 1\n\t"
        "v_add_f32_dpp %0, %0, %0 row_shr:1 row_mask:0xf bank_mask:0xf bound_ctrl:0\n\t"
        "v_add_f32_dpp %1, %1, %1 row_shr:1 row_mask:0xf bank_mask:0xf bound_ctrl:0\n\t"
        "s_nop 0\n\t"
        "v_add_f32_dpp %0, %0, %0 row_shr:2 row_mask:0xf bank_mask:0xf bound_ctrl:0\n\t"
        "v_add_f32_dpp %1, %1, %1 row_shr:2 row_mask:0xf bank_mask:0xf bound_ctrl:0\n\t"
        "s_nop 0\n\t"
        "v_add_f32_dpp %0, %0, %0 row_shr:4 row_mask:0xf bank_mask:0xf bound_ctrl:0\n\t"
        "v_add_f32_dpp %1, %1, %1 row_shr:4 row_mask:0xf bank_mask:0xf bound_ctrl:0\n\t"
        "s_nop 0\n\t"
        "v_add_f32_dpp %0, %0, %0 row_shr:8 row_mask:0xf bank_mask:0xf bound_ctrl:0\n\t"
        "v_add_f32_dpp %1, %1, %1 row_shr:8 row_mask:0xf bank_mask:0xf bound_ctrl:0\n\t"
        "s_nop 0\n\t"
        "v_add_f32_dpp %0, %0, %0 row_bcast:15 row_mask:0xa bank_mask:0xf bound_ctrl:0\n\t"
        "v_add_f32_dpp %1, %1, %1 row_bcast:15 row_mask:0xa bank_mask:0xf bound_ctrl:0\n\t"
        "s_nop 0\n\t"
        "v_add_f32_dpp %0, %0, %0 row_bcast:31 row_mask:0xc bank_mask:0xf bound_ctrl:0\n\t"
        "v_add_f32_dpp %1, %1, %1 row_bcast:31 row_mask:0xc bank_mask:0xf bound_ctrl:0\n\t"
        "s_nop 1"
        : "+v"(a), "+v"(b));
}

// Pre-pack W1 into component-paired layout (R14-R18 verified).
__global__ void pack_kernel(const float* __restrict__ W1,
                            float* __restrict__ pw) {
    const int row = blockIdx.x;     // 128
    const int a   = threadIdx.x;    // 32
    const float* rp = W1 + row * 128;
    float* out = pw + row * 128;
    out[2*a]          = rp[3*a];
    out[2*a + 1]      = rp[3*a + 1];
    out[64 + 2*a]     = rp[3*a + 2];
    out[64 + 2*a + 1] = rp[96 + a];
}

// R31 = R30's single-wave merge (dataflow proven bit-exact on HW, absmax
// 0.0) + weights in AGPRs. Arch demand ~240 < 256 cap -> no scratch.
// Weight access macros keep R30's operand orders exactly (aread returns
// identical bits to the old VGPR-resident values).
#define WXA(k) aread(W0x[k], W0y[k])
#define WZA(k) aread(W1x[k], W1y[k])
#define WXB(k) aread(W2x[k], W2y[k])
#define WZB(k) aread(W3x[k], W3y[k])

__global__ __launch_bounds__(64)
__attribute__((amdgpu_waves_per_eu(1, 1)))
void sim_kernel(const float* __restrict__ target_pos,
                const float* __restrict__ logsigma,
                const float* __restrict__ x_inits,
                const float* __restrict__ pw,
                const float* __restrict__ b1,
                const float* __restrict__ W2,
                const float* __restrict__ b2,
                float2* __restrict__ ws) {
    const int agent = blockIdx.x;
    const int lane  = threadIdx.x;   // 0..63 — single wave
    const int rowA = lane;
    const int rowB = lane + 64;

    const float tx0 = uniformf(target_pos[0]), ty0 = uniformf(target_pos[1]);
    const float tx1 = uniformf(target_pos[2]), ty1 = uniformf(target_pos[3]);
    const float tx2 = uniformf(target_pos[4]), ty2 = uniformf(target_pos[5]);
    const float is0 = uniformf(1.0f / expf(logsigma[0]));
    const float is1 = uniformf(1.0f / expf(logsigma[1]));
    const float is2 = uniformf(1.0f / expf(logsigma[2]));

    // ALL 32 ages in AGPRs: 8 float arrays x 32 = 256 AGPRs exactly.
    // W0=WxyA, W1=WzcA, W2=WxyB, W3=WzcB (x/y components split).
    float W0x[32], W0y[32], W1x[32], W1y[32];
    float W2x[32], W2y[32], W3x[32], W3y[32];
    {
        const float* baseA = pw + rowA * 128;
        const float* baseB = pw + rowB * 128;
        #pragma unroll
        for (int i = 0; i < 32; ++i) {
            awrite(W0x[i], W0y[i], opaque_load8(baseA + 2 * i));
            awrite(W1x[i], W1y[i], opaque_load8(baseA + 64 + 2 * i));
            awrite(W2x[i], W2y[i], opaque_load8(baseB + 2 * i));
            awrite(W3x[i], W3y[i], opaque_load8(baseB + 64 + 2 * i));
        }
    }
    const float b1A = b1[rowA], b1B = b1[rowB];
    const float w20A = W2[rowA], w20B = W2[rowB];
    const float w21A = W2[HIDDEN + rowA], w21B = W2[HIDDEN + rowB];
    const float b2x = uniformf(b2[0]), b2y = uniformf(b2[1]);

    auto conc = [&](float px, float py) {
        float dx0 = px - tx0, dy0 = py - ty0;
        float dx1 = px - tx1, dy1 = py - ty1;
        float dx2 = px - tx2, dy2 = py - ty2;
        float cc  = is0 * __expf(-(dx0*dx0 + dy0*dy0) * is0);
        cc       += is1 * __expf(-(dx1*dx1 + dy1*dy1) * is1);
        cc       += is2 * __expf(-(dx2*dx2 + dy2*dy2) * is2);
        return cc;
    };

    float x  = uniformf(x_inits[3 * agent]);
    float y  = uniformf(x_inits[3 * agent + 1]);
    float th = uniformf(x_inits[3 * agent + 2]);
    float c  = conc(x, y);

    // Register state (arch VGPRs): ~240 total.
    v2f RA[16], RB[16];          // ages 0-15 partial ring
    v2f PA[20], PB[20];          // ages 16-31 partial ring
    float plA[16], plB[16];      // shipped partial_1 ring
    v2f eA_xy[4], eA_zc[4];      // state buffers
    v2f eB_xy[4], eB_zc[4];
    float S_c = 0.f, S_u = 0.f;

    {   // seeds — R30 verbatim, weights via aread (identical bits)
        v2f exy0 = {x, y}, ezc0 = {th, c};
        {   v2f aA = {0.f,0.f}, aB = {0.f,0.f};
            #pragma unroll
            for (int k = 15; k >= 0; --k) {
                v2f wxa = WXA(k), wza = WZA(k);
                v2f wxb = WXB(k), wzb = WZB(k);
                aA = wxa*exy0 + aA;  aA = wza*ezc0 + aA;
                aB = wxb*exy0 + aB;  aB = wzb*ezc0 + aB;
                RA[k] = aA;  RB[k] = aB;
            }
        }
        #pragma unroll
        for (int i = 15; i < 20; ++i) { PA[i] = (v2f){0.f,0.f}; PB[i] = (v2f){0.f,0.f}; }
        {   v2f aA = {0.f,0.f}, aB = {0.f,0.f};
            #pragma unroll
            for (int k = 15; k >= 1; --k) {
                v2f wxa = WXA(16+k), wza = WZA(16+k);
                v2f wxb = WXB(16+k), wzb = WZB(16+k);
                aA = wxa*exy0 + aA;  aA = wza*ezc0 + aA;
                aB = wxb*exy0 + aB;  aB = wzb*ezc0 + aB;
                PA[k-1] = aA;  PB[k-1] = aB;
            }
            v2f wxa0 = WXA(16), wza0 = WZA(16);
            v2f wxb0 = WXB(16), wzb0 = WZB(16);
            v2f fA = wxa0*exy0 + aA;  fA = wza0*ezc0 + fA;
            v2f fB = wxb0*exy0 + aB;  fB = wzb0*ezc0 + fB;
            float fullA = fA.x + fA.y, fullB = fB.x + fB.y;
            #pragma unroll
            for (int s = 0; s <= 8; ++s) { plA[s] = fullA; plB[s] = fullB; }
        }
        #pragma unroll
        for (int i = 0; i < 4; ++i) { eB_xy[i] = exy0; eB_zc[i] = ezc0; }
    }

    // producer batch, R30 verbatim (overwrite-first), ages at +16
    auto h1_batch = [&](v2f (&px)[4], v2f (&pz)[4], int n) {
        #pragma unroll
        for (int kk = 0; kk < 16; ++kk) {
            v2f wxa = WXA(16+kk), wza = WZA(16+kk);
            v2f wxb = WXB(16+kk), wzb = WZB(16+kk);
            #pragma unroll
            for (int i = 0; i < 4; ++i) {
                const int idx = i + kk;
                if (i == 3 && kk >= 12) {
                    PA[idx] = wxa*px[i];
                    PA[idx] = wza*pz[i] + PA[idx];
                    PB[idx] = wxb*px[i];
                    PB[idx] = wzb*pz[i] + PB[idx];
                } else {
                    PA[idx] = wxa*px[i] + PA[idx];
                    PA[idx] = wza*pz[i] + PA[idx];
                    PB[idx] = wxb*px[i] + PB[idx];
                    PB[idx] = wzb*pz[i] + PB[idx];
                }
            }
        }
        #pragma unroll
        for (int i = 0; i < 4; ++i) {
            plA[(9 + 4*n + i) & 15] = PA[i].x + PA[i].y;
            plB[(9 + 4*n + i) & 15] = PB[i].x + PB[i].y;
        }
        #pragma unroll
        for (int i = 0; i < 16; ++i) { PA[i] = PA[i+4]; PB[i] = PB[i+4]; }
    };

    // prologue h1(0): inputs e0 x4 (eB), ships pl[9..12]
    h1_batch(eB_xy, eB_zc, 0);

    auto h0_step = [&](int j, v2f (&bx)[4], v2f (&bz)[4]) {
        float hA = fmaxf((RA[j & 15].x + RA[j & 15].y) + plA[j & 15] + b1A, 0.f);
        float hB = fmaxf((RB[j & 15].x + RB[j & 15].y) + plB[j & 15] + b1B, 0.f);
        float r0 = fmaf(w20A, hA, w20B * hB);
        float r1 = fmaf(w21A, hA, w21B * hB);
        wave_sum2_dpp(r0, r1);
        float s0 = __builtin_bit_cast(float,
            __builtin_amdgcn_readlane(__builtin_bit_cast(int, r0), 63));
        float s1 = __builtin_bit_cast(float,
            __builtin_amdgcn_readlane(__builtin_bit_cast(int, r1), 63));
        float v  = tanh_fast(s0 + b2x);
        float wv = tanh_fast(s1 + b2y);
        S_u += v * v + wv * wv;
        float sn = __sinf(th), cs = __cosf(th);
        float dv = DT * v;
        x  = fmaf(dv, cs, x);
        y  = fmaf(dv, sn, y);
        th = fmaf(DT, wv, th);
        c  = conc(x, y);
        S_c += c;
        v2f exy = {x, y}, ezc = {th, c};
        bx[j & 3] = exy;  bz[j & 3] = ezc;
        // urgent taps: k <= 2 - (j&3)
        #pragma unroll
        for (int k = 0; k < 3; ++k) {
            if (k <= 2 - (j & 3)) {
                const int m = (j + 1 + k) & 15;
                v2f wxa = WXA(k), wza = WZA(k);
                v2f wxb = WXB(k), wzb = WZB(k);
                RA[m] = wxa*exy + RA[m];  RA[m] = wza*ezc + RA[m];
                RB[m] = wxb*exy + RB[m];  RB[m] = wzb*ezc + RB[m];
            }
        }
    };
    auto h0_batch = [&](int q, v2f (&bx)[4], v2f (&bz)[4]) {
        #pragma unroll
        for (int kk = 0; kk < 16; ++kk) {
            v2f wxa = WXA(kk), wza = WZA(kk);
            v2f wxb = WXB(kk), wzb = WZB(kk);
            #pragma unroll
            for (int i = 0; i < 4; ++i) {
                if (kk >= 3 - i) {
                    const int m = (4*q + i + 1 + kk) & 15;
                    if (i == 3 && kk >= 12) {
                        RA[m] = wxa*bx[i];
                        RA[m] = wza*bz[i] + RA[m];
                        RB[m] = wxb*bx[i];
                        RB[m] = wzb*bz[i] + RB[m];
                    } else {
                        RA[m] = wxa*bx[i] + RA[m];
                        RA[m] = wza*bz[i] + RA[m];
                        RB[m] = wxb*bx[i] + RB[m];
                        RB[m] = wzb*bz[i] + RB[m];
                    }
                }
            }
        }
    };

    #pragma unroll 1
    for (int b = 0; b < 62; ++b) {
        // group 0: steps 0-3 -> eA
        h0_step(0, eA_xy, eA_zc);  h0_step(1, eA_xy, eA_zc);
        h0_step(2, eA_xy, eA_zc);  h0_step(3, eA_xy, eA_zc);
        h0_batch(0, eA_xy, eA_zc);
        h1_batch(eB_xy, eB_zc, 1);          // inputs: prev window grp 3 (or e0)
        // group 1: steps 4-7 -> eB
        h0_step(4, eB_xy, eB_zc);  h0_step(5, eB_xy, eB_zc);
        h0_step(6, eB_xy, eB_zc);  h0_step(7, eB_xy, eB_zc);
        h0_batch(1, eB_xy, eB_zc);
        h1_batch(eA_xy, eA_zc, 2);          // inputs: this window grp 0
        // group 2: steps 8-11 -> eA
        h0_step(8, eA_xy, eA_zc);   h0_step(9, eA_xy, eA_zc);
        h0_step(10, eA_xy, eA_zc);  h0_step(11, eA_xy, eA_zc);
        h0_batch(2, eA_xy, eA_zc);
        h1_batch(eB_xy, eB_zc, 3);          // inputs: this window grp 1
        // group 3: steps 12-15 -> eB
        h0_step(12, eB_xy, eB_zc);  h0_step(13, eB_xy, eB_zc);
        h0_step(14, eB_xy, eB_zc);  h0_step(15, eB_xy, eB_zc);
        h0_batch(3, eB_xy, eB_zc);
        h1_batch(eA_xy, eA_zc, 0);          // inputs: this window grp 2
    }
    // remainder: steps 992..999; pl[0..7] shipped during window 61.
    h0_step(0, eA_xy, eA_zc);  h0_step(1, eA_xy, eA_zc);
    h0_step(2, eA_xy, eA_zc);  h0_step(3, eA_xy, eA_zc);
    h0_batch(0, eA_xy, eA_zc);
    h0_step(4, eB_xy, eB_zc);  h0_step(5, eB_xy, eB_zc);
    h0_step(6, eB_xy, eB_zc);  h0_step(7, eB_xy, eB_zc);

    if (lane == 0) ws[agent] = make_float2(S_c, S_u);
}

__global__ void reduce_kernel(const float2* __restrict__ ws,
                              float* __restrict__ out) {
    const int tid = threadIdx.x;  // 256 threads
    float sc = 0.f, su = 0.f;
    for (int i = tid; i < N_AGENTS; i += 256) {
        float2 v = ws[i];
        sc += v.x;
        su += v.y;
    }
    #pragma unroll
    for (int off = 32; off > 0; off >>= 1) {
        sc += __shfl_xor(sc, off);
        su += __shfl_xor(su, off);
    }
    __shared__ float2 partw[4];
    int wave = tid >> 6;
    if ((tid & 63) == 0) partw[wave] = make_float2(sc, su);
    __syncthreads();
    if (tid == 0) {
        float SC = partw[0].x + partw[1].x + partw[2].x + partw[3].x;
        float SU = partw[0].y + partw[1].y + partw[2].y + partw[3].y;
        const float invNT  = 1.0f / (float)(N_AGENTS * T_STEPS);
        const float invNT2 = 1.0f / (float)(N_AGENTS * T_STEPS * 2);
        out[0] = -SC * invNT + SU * invNT2;
    }
}

extern "C" void kernel_launch(void* const* d_in, const int* in_sizes, int n_in,
                              void* d_out, int out_size, void* d_ws, size_t ws_size,
                              hipStream_t stream) {
    const float* target_pos = (const float*)d_in[0];
    const float* logsigma   = (const float*)d_in[1];
    const float* x_inits    = (const float*)d_in[2];
    const float* W1         = (const float*)d_in[3];
    const float* b1         = (const float*)d_in[4];
    const float* W2         = (const float*)d_in[5];
    const float* b2         = (const float*)d_in[6];

    float*  pw   = (float*)d_ws;                          // 64 KB packed W1
    float2* sums = (float2*)((char*)d_ws + 64 * 1024);    // per-agent sums

    pack_kernel<<<HIDDEN, 32, 0, stream>>>(W1, pw);
    sim_kernel<<<N_AGENTS, 64, 0, stream>>>(target_pos, logsigma, x_inits,
                                            pw, b1, W2, b2, sums);
    reduce_kernel<<<1, 256, 0, stream>>>(sums, (float*)d_out);
}

// Round 14
// 630.410 us; speedup vs baseline: 4.3657x; 4.3657x over previous
//
#include <hip/hip_runtime.h>

#define T_STEPS 1000
#define DT 0.1f
#define HIDDEN 128
#define N_AGENTS 1024

typedef float v2f __attribute__((ext_vector_type(2)));

// tanh(x) = 1 - 2/(exp(2x)+1); exact at +/-inf, ~1e-7 rel error.
__device__ __forceinline__ float tanh_fast(float x) {
    float e = __expf(2.0f * x);
    return 1.0f - 2.0f * __builtin_amdgcn_rcpf(e + 1.0f);
}

// Opaque 8B load (R13-R18 proven residency mechanism).
__device__ __forceinline__ v2f opaque_load8(const float* p) {
    v2f v;
    asm volatile("global_load_dwordx2 %0, %1, off\n\ts_waitcnt vmcnt(0)"
                 : "=v"(v)
                 : "v"((unsigned long long)(uintptr_t)p)
                 : "memory");
    return v;
}

__device__ __forceinline__ float uniformf(float v) {
    return __builtin_bit_cast(float,
        __builtin_amdgcn_readfirstlane(__builtin_bit_cast(int, v)));
}

// R25: DUAL fused DPP reduction (bitwise-identical adds, 1 instr/stage,
// interleaved chains cover VALU->DPP wait states). Proven -2.9%.
// Volatile form (R29 A/B: non-volatile neutral-to-worse).
__device__ __forceinline__ void wave_sum2_dpp(float& a, float& b) {
    asm volatile(
        "s_nop 1\n\t"
        "v_add_f32_dpp %0, %0, %0 row_shr:1 row_mask:0xf bank_mask:0xf bound_ctrl:0\n\t"
        "v_add_f32_dpp %1, %1, %1 row_shr:1 row_mask:0xf bank_mask:0xf bound_ctrl:0\n\t"
        "s_nop 0\n\t"
        "v_add_f32_dpp %0, %0, %0 row_shr:2 row_mask:0xf bank_mask:0xf bound_ctrl:0\n\t"
        "v_add_f32_dpp %1, %1, %1 row_shr:2 row_mask:0xf bank_mask:0xf bound_ctrl:0\n\t"
        "s_nop 0\n\t"
        "v_add_f32_dpp %0, %0, %0 row_shr:4 row_mask:0xf bank_mask:0xf bound_ctrl:0\n\t"
        "v_add_f32_dpp %1, %1, %1 row_shr:4 row_mask:0xf bank_mask:0xf bound_ctrl:0\n\t"
        "s_nop 0\n\t"
        "v_add_f32_dpp %0, %0, %0 row_shr:8 row_mask:0xf bank_mask:0xf bound_ctrl:0\n\t"
        "v_add_f32_dpp %1, %1, %1 row_shr:8 row_mask:0xf bank_mask:0xf bound_ctrl:0\n\t"
        "s_nop 0\n\t"
        "v_add_f32_dpp %0, %0, %0 row_bcast:15 row_mask:0xa bank_mask:0xf bound_ctrl:0\n\t"
        "v_add_f32_dpp %1, %1, %1 row_bcast:15 row_mask:0xa bank_mask:0xf bound_ctrl:0\n\t"
        "s_nop 0\n\t"
        "v_add_f32_dpp %0, %0, %0 row_bcast:31 row_mask:0xc bank_mask:0xf bound_ctrl:0\n\t"
        "v_add_f32_dpp %1, %1, %1 row_bcast:31 row_mask:0xc bank_mask:0xf bound_ctrl:0\n\t"
        "s_nop 1"
        : "+v"(a), "+v"(b));
}

// Pre-pack W1 into component-paired layout (R14-R18 verified).
__global__ void pack_kernel(const float* __restrict__ W1,
                            float* __restrict__ pw) {
    const int row = blockIdx.x;     // 128
    const int a   = threadIdx.x;    // 32
    const float* rp = W1 + row * 128;
    float* out = pw + row * 128;
    out[2*a]          = rp[3*a];
    out[2*a + 1]      = rp[3*a + 1];
    out[64 + 2*a]     = rp[3*a + 2];
    out[64 + 2*a + 1] = rp[96 + a];
}

// R33 = R28 (632.7us anchor, absmax 0.0; single-wave merge line CLOSED by
// R30 spill / R31 copy-tax / R32 ISA-reject: VOP3P can't read AGPRs) + ONE
// delta: SIN/COS SOFTWARE-PIPELINE. sn/cs depend only on the PREVIOUS
// step's th (they're computed before th's update), so compute them at the
// END of step j (right after th update) and consume in step j+1 -- same
// input bits, same functions, identical results; their trans-pipe latency
// now overlaps conc/taps/reduction instead of sitting on the critical
// chain between tanh and the x/y update.
__global__ __launch_bounds__(128)
__attribute__((amdgpu_waves_per_eu(2, 2)))
void sim_kernel(const float* __restrict__ target_pos,
                const float* __restrict__ logsigma,
                const float* __restrict__ x_inits,
                const float* __restrict__ pw,
                const float* __restrict__ b1,
                const float* __restrict__ W2,
                const float* __restrict__ b2,
                float2* __restrict__ ws) {
    const int agent = blockIdx.x;
    const int tid  = threadIdx.x;   // 0..127
    const int h    = tid >> 6;      // 0 = consumer, 1 = producer
    const int lane = tid & 63;
    const int rowA = lane;
    const int rowB = lane + 64;

    __shared__ float2 part1[32][64];        // h=1 -> h=0 partial ring
    __shared__ float4 e4buf[16];            // state ring, 16-deep

    if (h == 0) __builtin_amdgcn_s_setprio(1);   // R23-proven safe/neutral

    const float tx0 = uniformf(target_pos[0]), ty0 = uniformf(target_pos[1]);
    const float tx1 = uniformf(target_pos[2]), ty1 = uniformf(target_pos[3]);
    const float tx2 = uniformf(target_pos[4]), ty2 = uniformf(target_pos[5]);
    const float is0 = uniformf(1.0f / expf(logsigma[0]));
    const float is1 = uniformf(1.0f / expf(logsigma[1]));
    const float is2 = uniformf(1.0f / expf(logsigma[2]));

    // Paired weights for ages 16h..16h+15, rows A and B: 64 v2f pinned.
    v2f WxyA[16], WzcA[16], WxyB[16], WzcB[16];
    {
        const float* baseA = pw + rowA * 128;
        const float* baseB = pw + rowB * 128;
        #pragma unroll
        for (int i = 0; i < 16; ++i) {
            WxyA[i] = opaque_load8(baseA + 32 * h + 2 * i);
            WzcA[i] = opaque_load8(baseA + 64 + 32 * h + 2 * i);
            WxyB[i] = opaque_load8(baseB + 32 * h + 2 * i);
            WzcB[i] = opaque_load8(baseB + 64 + 32 * h + 2 * i);
        }
    }
    const float b1A = b1[rowA], b1B = b1[rowB];
    const float w20A = W2[rowA], w20B = W2[rowB];
    const float w21A = W2[HIDDEN + rowA], w21B = W2[HIDDEN + rowB];
    const float b2x = uniformf(b2[0]), b2y = uniformf(b2[1]);

    auto conc = [&](float px, float py) {
        float dx0 = px - tx0, dy0 = py - ty0;
        float dx1 = px - tx1, dy1 = py - ty1;
        float dx2 = px - tx2, dy2 = py - ty2;
        float cc  = is0 * __expf(-(dx0*dx0 + dy0*dy0) * is0);
        cc       += is1 * __expf(-(dx1*dx1 + dy1*dy1) * is1);
        cc       += is2 * __expf(-(dx2*dx2 + dy2*dy2) * is2);
        return cc;
    };

    float x  = uniformf(x_inits[3 * agent]);
    float y  = uniformf(x_inits[3 * agent + 1]);
    float th = uniformf(x_inits[3 * agent + 2]);
    float c  = conc(x, y);

    if (h == 0) {
        // ---------------- consumer wave ----------------
        v2f RA[16], RB[16];
        {   // seed slot s: sum_{k=s..15} W[k]·e(0)
            v2f exy0 = {x, y}, ezc0 = {th, c};
            v2f aA = {0.f,0.f}, aB = {0.f,0.f};
            #pragma unroll
            for (int k = 15; k >= 0; --k) {
                aA = WxyA[k]*exy0 + aA;  aA = WzcA[k]*ezc0 + aA;
                aB = WxyB[k]*exy0 + aB;  aB = WzcB[k]*ezc0 + aB;
                RA[k] = aA;  RB[k] = aB;
            }
            if (lane == 0) {
                float4 e0 = make_float4(x, y, th, c);
                #pragma unroll
                for (int m = 9; m < 16; ++m) e4buf[m] = e0;
                e4buf[0] = e0;
            }
        }
        // R33: sin/cos pipeline seed — values for step 0 (th = initial th,
        // exactly what the old code computed inside step 0).
        float sn = __sinf(th), cs = __cosf(th);
        __syncthreads();              // seed barrier (both waves)
        float2 p0 = part1[0][lane];   // pl for step 0
        float2 p1, p2, p3;            // prefetch pipeline (filled after B0)
        v2f es_xy[4], es_zc[4];
        float S_c = 0.f, S_u = 0.f;

        auto h0_step = [&](int j, int s16, bool rd) {
            float hA = fmaxf((RA[j].x + RA[j].y) + p0.x + b1A, 0.f);
            float hB = fmaxf((RB[j].x + RB[j].y) + p0.y + b1B, 0.f);
            // R24: no slot zeroing -- batch (i==3,kk>=12) tap overwrites.
            float r0 = fmaf(w20A, hA, w20B * hB);
            float r1 = fmaf(w21A, hA, w21B * hB);
            wave_sum2_dpp(r0, r1);    // R25: fused dual reduction
            float s0 = __builtin_bit_cast(float,
                __builtin_amdgcn_readlane(__builtin_bit_cast(int, r0), 63));
            float s1 = __builtin_bit_cast(float,
                __builtin_amdgcn_readlane(__builtin_bit_cast(int, r1), 63));
            float v  = tanh_fast(s0 + b2x);
            float wv = tanh_fast(s1 + b2y);
            S_u += v * v + wv * wv;
            // R33: use PIPELINED sn/cs (computed from th at end of prev
            // step == old th here -- identical bits to the old in-step
            // __sinf/__cosf placement).
            float dv = DT * v;
            x  = fmaf(dv, cs, x);
            y  = fmaf(dv, sn, y);
            th = fmaf(DT, wv, th);
            sn = __sinf(th);  cs = __cosf(th);   // for step j+1, off-chain
            c  = conc(x, y);
            S_c += c;
            if (lane == 0) e4buf[(j + 1) & 15] = make_float4(x, y, th, c);
            v2f exy = {x, y}, ezc = {th, c};
            es_xy[j & 3] = exy;  es_zc[j & 3] = ezc;
            // urgent taps: k <= 2 - (j&3)
            #pragma unroll
            for (int k = 0; k < 3; ++k) {
                if (k <= 2 - (j & 3)) {
                    const int m = (j + 1 + k) & 15;
                    RA[m] = WxyA[k]*exy + RA[m];  RA[m] = WzcA[k]*ezc + RA[m];
                    RB[m] = WxyB[k]*exy + RB[m];  RB[m] = WzcB[k]*ezc + RB[m];
                }
            }
            // R28: rotate prefetch pipeline; read 4 ahead when published
            p0 = p1;  p1 = p2;  p2 = p3;
            if (rd) p3 = part1[(s16 + j + 4) & 31][lane];
        };
        auto h0_batch = [&](int q) {   // lazy taps of states e(.+4q+1..+4)
            #pragma unroll
            for (int kk = 0; kk < 16; ++kk) {
                #pragma unroll
                for (int i = 0; i < 4; ++i) {
                    if (kk >= 3 - i) {
                        const int m = (4*q + i + 1 + kk) & 15;
                        if (i == 3 && kk >= 12) {
                            // first write since consume -> overwrite
                            RA[m] = WxyA[kk]*es_xy[i];
                            RA[m] = WzcA[kk]*es_zc[i] + RA[m];
                            RB[m] = WxyB[kk]*es_xy[i];
                            RB[m] = WzcB[kk]*es_zc[i] + RB[m];
                        } else {
                            RA[m] = WxyA[kk]*es_xy[i] + RA[m];
                            RA[m] = WzcA[kk]*es_zc[i] + RA[m];
                            RB[m] = WxyB[kk]*es_xy[i] + RB[m];
                            RB[m] = WzcB[kk]*es_zc[i] + RB[m];
                        }
                    }
                }
            }
        };

        #pragma unroll 1
        for (int b = 0; b < 62; ++b) {
            const int s16 = (b & 1) << 4;
            __syncthreads();                       // B0
            p1 = part1[(s16 + 1) & 31][lane];      // rel 1..3: published
            p2 = part1[(s16 + 2) & 31][lane];      // in window b-1 (or seed)
            p3 = part1[(s16 + 3) & 31][lane];
            h0_step(0, s16, true);  h0_step(1, s16, true);
            h0_step(2, s16, true);  h0_step(3, s16, true);
            h0_batch(0);
            h0_step(4, s16, true);  h0_step(5, s16, false);
            h0_step(6, s16, false); h0_step(7, s16, false);
            h0_batch(1);
            __syncthreads();                       // B1
            p1 = part1[(s16 + 9) & 31][lane];      // rel 9..11: published
            p2 = part1[(s16 + 10) & 31][lane];     // by batches 0,1 -> B1
            p3 = part1[(s16 + 11) & 31][lane];
            h0_step(8, s16, true);   h0_step(9, s16, true);
            h0_step(10, s16, true);  h0_step(11, s16, true);
            h0_batch(2);
            h0_step(12, s16, true);  h0_step(13, s16, false);
            h0_step(14, s16, false); h0_step(15, s16, false);
            h0_batch(3);
        }
        // remainder: steps 992..999 (b=62, s16=0); pl up to abs 1000
        // shipped by window 61 batch3 (16*61+24 = 1000) -> published at B0.
        __syncthreads();
        p1 = part1[1][lane];
        p2 = part1[2][lane];
        p3 = part1[3][lane];
        h0_step(0, 0, true);  h0_step(1, 0, true);
        h0_step(2, 0, true);  h0_step(3, 0, true);
        h0_batch(0);
        h0_step(4, 0, true);  h0_step(5, 0, false);
        h0_step(6, 0, false); h0_step(7, 0, false);

        if (lane == 0) ws[agent] = make_float2(S_c, S_u);
    } else {
        // ---------------- producer wave (R27: overwrite-first) ----------
        v2f PA[20], PB[20];
        {   // ring seed: PA[idx] = sum_{k=idx+1..15} W[k]·e(0), idx 0..14
            v2f exy0 = {x, y}, ezc0 = {th, c};
            #pragma unroll
            for (int i = 15; i < 20; ++i) { PA[i] = (v2f){0.f,0.f}; PB[i] = (v2f){0.f,0.f}; }
            v2f aA = {0.f,0.f}, aB = {0.f,0.f};
            #pragma unroll
            for (int k = 15; k >= 1; --k) {
                aA = WxyA[k]*exy0 + aA;  aA = WzcA[k]*ezc0 + aA;
                aB = WxyB[k]*exy0 + aB;  aB = WzcB[k]*ezc0 + aB;
                PA[k-1] = aA;  PB[k-1] = aB;
            }
            // part1 prefill s=0..8: full 16-tap sum
            v2f fA = WxyA[0]*exy0 + aA;  fA = WzcA[0]*ezc0 + fA;
            v2f fB = WxyB[0]*exy0 + aB;  fB = WzcB[0]*ezc0 + fB;
            float2 full = make_float2(fA.x + fA.y, fB.x + fB.y);
            #pragma unroll
            for (int s = 0; s <= 8; ++s) part1[s][lane] = full;
        }
        __syncthreads();              // seed barrier

        auto h1_batch = [&](int n, int b1w) {
            // read 4 states e(16b-7+4n .. +3 more): e4buf[(9+4n+i)&15]
            v2f pxy[4], pzc[4];
            #pragma unroll
            for (int i = 0; i < 4; ++i) {
                float4 e = e4buf[(9 + 4*n + i) & 15];
                pxy[i] = (v2f){e.x, e.y};
                pzc[i] = (v2f){e.z, e.w};
            }
            // k-outer push; (i==3,kk>=12) = first writers of recycled
            // slots 15..18 -> overwrite (replaces tail zeroing).
            #pragma unroll
            for (int kk = 0; kk < 16; ++kk) {
                #pragma unroll
                for (int i = 0; i < 4; ++i) {
                    const int idx = i + kk;
                    if (i == 3 && kk >= 12) {
                        PA[idx] = WxyA[kk]*pxy[i];
                        PA[idx] = WzcA[kk]*pzc[i] + PA[idx];
                        PB[idx] = WxyB[kk]*pxy[i];
                        PB[idx] = WzcB[kk]*pzc[i] + PB[idx];
                    } else {
                        PA[idx] = WxyA[kk]*pxy[i] + PA[idx];
                        PA[idx] = WzcA[kk]*pzc[i] + PA[idx];
                        PB[idx] = WxyB[kk]*pxy[i] + PB[idx];
                        PB[idx] = WzcB[kk]*pzc[i] + PB[idx];
                    }
                }
            }
            // ship 4 completed partials: s = 16b + 9+4n + i
            #pragma unroll
            for (int i = 0; i < 4; ++i) {
                part1[(b1w * 16 + 9 + 4*n + i) & 31][lane] =
                    make_float2(PA[i].x + PA[i].y, PB[i].x + PB[i].y);
            }
            // rotate by 4; no tail zeroing (overwrites handle 15..18;
            // PA[19]/PB[19] stay 0 forever: seeded 0, never tapped,
            // never rotated-into).
            #pragma unroll
            for (int i = 0; i < 16; ++i) { PA[i] = PA[i+4]; PB[i] = PB[i+4]; }
        };

        #pragma unroll 1
        for (int b = 0; b < 62; ++b) {
            const int b1w = b & 1;
            __syncthreads();
            h1_batch(0, b1w);
            h1_batch(1, b1w);
            __syncthreads();
            h1_batch(2, b1w);
            h1_batch(3, b1w);
        }
        __syncthreads();   // remainder barrier (match h0); nothing to ship
    }
}

__global__ void reduce_kernel(const float2* __restrict__ ws,
                              float* __restrict__ out) {
    const int tid = threadIdx.x;  // 256 threads
    float sc = 0.f, su = 0.f;
    for (int i = tid; i < N_AGENTS; i += 256) {
        float2 v = ws[i];
        sc += v.x;
        su += v.y;
    }
    #pragma unroll
    for (int off = 32; off > 0; off >>= 1) {
        sc += __shfl_xor(sc, off);
        su += __shfl_xor(su, off);
    }
    __shared__ float2 partw[4];
    int wave = tid >> 6;
    if ((tid & 63) == 0) partw[wave] = make_float2(sc, su);
    __syncthreads();
    if (tid == 0) {
        float SC = partw[0].x + partw[1].x + partw[2].x + partw[3].x;
        float SU = partw[0].y + partw[1].y + partw[2].y + partw[3].y;
        const float invNT  = 1.0f / (float)(N_AGENTS * T_STEPS);
        const float invNT2 = 1.0f / (float)(N_AGENTS * T_STEPS * 2);
        out[0] = -SC * invNT + SU * invNT2;
    }
}

extern "C" void kernel_launch(void* const* d_in, const int* in_sizes, int n_in,
                              void* d_out, int out_size, void* d_ws, size_t ws_size,
                              hipStream_t stream) {
    const float* target_pos = (const float*)d_in[0];
    const float* logsigma   = (const float*)d_in[1];
    const float* x_inits    = (const float*)d_in[2];
    const float* W1         = (const float*)d_in[3];
    const float* b1         = (const float*)d_in[4];
    const float* W2         = (const float*)d_in[5];
    const float* b2         = (const float*)d_in[6];

    float*  pw   = (float*)d_ws;                          // 64 KB packed W1
    float2* sums = (float2*)((char*)d_ws + 64 * 1024);    // per-agent sums

    pack_kernel<<<HIDDEN, 32, 0, stream>>>(W1, pw);
    sim_kernel<<<N_AGENTS, 128, 0, stream>>>(target_pos, logsigma, x_inits,
                                             pw, b1, W2, b2, sums);
    reduce_kernel<<<1, 256, 0, stream>>>(sums, (float*)d_out);
}

// Round 15
// 625.680 us; speedup vs baseline: 4.3987x; 1.0076x over previous
//
#include <hip/hip_runtime.h>

#define T_STEPS 1000
#define DT 0.1f
#define HIDDEN 128
#define N_AGENTS 1024

typedef float v2f __attribute__((ext_vector_type(2)));

// tanh(x) = 1 - 2/(exp(2x)+1); exact at +/-inf, ~1e-7 rel error.
__device__ __forceinline__ float tanh_fast(float x) {
    float e = __expf(2.0f * x);
    return 1.0f - 2.0f * __builtin_amdgcn_rcpf(e + 1.0f);
}

// Opaque 8B load (R13-R18 proven residency mechanism).
__device__ __forceinline__ v2f opaque_load8(const float* p) {
    v2f v;
    asm volatile("global_load_dwordx2 %0, %1, off\n\ts_waitcnt vmcnt(0)"
                 : "=v"(v)
                 : "v"((unsigned long long)(uintptr_t)p)
                 : "memory");
    return v;
}

__device__ __forceinline__ float uniformf(float v) {
    return __builtin_bit_cast(float,
        __builtin_amdgcn_readfirstlane(__builtin_bit_cast(int, v)));
}

// R25: DUAL fused DPP reduction (bitwise-identical adds, 1 instr/stage,
// interleaved chains cover VALU->DPP wait states). Proven -2.9%.
// Volatile form (R29 A/B: non-volatile neutral-to-worse).
__device__ __forceinline__ void wave_sum2_dpp(float& a, float& b) {
    asm volatile(
        "s_nop 1\n\t"
        "v_add_f32_dpp %0, %0, %0 row_shr:1 row_mask:0xf bank_mask:0xf bound_ctrl:0\n\t"
        "v_add_f32_dpp %1, %1, %1 row_shr:1 row_mask:0xf bank_mask:0xf bound_ctrl:0\n\t"
        "s_nop 0\n\t"
        "v_add_f32_dpp %0, %0, %0 row_shr:2 row_mask:0xf bank_mask:0xf bound_ctrl:0\n\t"
        "v_add_f32_dpp %1, %1, %1 row_shr:2 row_mask:0xf bank_mask:0xf bound_ctrl:0\n\t"
        "s_nop 0\n\t"
        "v_add_f32_dpp %0, %0, %0 row_shr:4 row_mask:0xf bank_mask:0xf bound_ctrl:0\n\t"
        "v_add_f32_dpp %1, %1, %1 row_shr:4 row_mask:0xf bank_mask:0xf bound_ctrl:0\n\t"
        "s_nop 0\n\t"
        "v_add_f32_dpp %0, %0, %0 row_shr:8 row_mask:0xf bank_mask:0xf bound_ctrl:0\n\t"
        "v_add_f32_dpp %1, %1, %1 row_shr:8 row_mask:0xf bank_mask:0xf bound_ctrl:0\n\t"
        "s_nop 0\n\t"
        "v_add_f32_dpp %0, %0, %0 row_bcast:15 row_mask:0xa bank_mask:0xf bound_ctrl:0\n\t"
        "v_add_f32_dpp %1, %1, %1 row_bcast:15 row_mask:0xa bank_mask:0xf bound_ctrl:0\n\t"
        "s_nop 0\n\t"
        "v_add_f32_dpp %0, %0, %0 row_bcast:31 row_mask:0xc bank_mask:0xf bound_ctrl:0\n\t"
        "v_add_f32_dpp %1, %1, %1 row_bcast:31 row_mask:0xc bank_mask:0xf bound_ctrl:0\n\t"
        "s_nop 1"
        : "+v"(a), "+v"(b));
}

// Pre-pack W1 into component-paired layout (R14-R18 verified).
__global__ void pack_kernel(const float* __restrict__ W1,
                            float* __restrict__ pw) {
    const int row = blockIdx.x;     // 128
    const int a   = threadIdx.x;    // 32
    const float* rp = W1 + row * 128;
    float* out = pw + row * 128;
    out[2*a]          = rp[3*a];
    out[2*a + 1]      = rp[3*a + 1];
    out[64 + 2*a]     = rp[3*a + 2];
    out[64 + 2*a + 1] = rp[96 + a];
}

// R34 = R33 (630.4us anchor, absmax 0.0) + ONE delta: BATCHED e4buf WRITES.
// Old: per-step `if(lane==0) e4buf[(j+1)&15]=...` (~4-5 instr/step of
// cmp/exec/store overhead on the pacer). New: one masked region per 4-step
// group writing slots 4g+1..4g+4 from es_xy/es_zc (same values, same slots).
// Safety (all barrier-separated, per-slot verified): grp0->h1(2) after B1;
// grp1->h1(3) after B1; grp2->h1(0) after next B0; grp3 (incl slot 0)
// ->h1(1) after next B0. Slot-0 WAR: producer's h1(1) read happens before
// B1, our write after B1 -> ordered. Seed writes unchanged.
__global__ __launch_bounds__(128)
__attribute__((amdgpu_waves_per_eu(2, 2)))
void sim_kernel(const float* __restrict__ target_pos,
                const float* __restrict__ logsigma,
                const float* __restrict__ x_inits,
                const float* __restrict__ pw,
                const float* __restrict__ b1,
                const float* __restrict__ W2,
                const float* __restrict__ b2,
                float2* __restrict__ ws) {
    const int agent = blockIdx.x;
    const int tid  = threadIdx.x;   // 0..127
    const int h    = tid >> 6;      // 0 = consumer, 1 = producer
    const int lane = tid & 63;
    const int rowA = lane;
    const int rowB = lane + 64;

    __shared__ float2 part1[32][64];        // h=1 -> h=0 partial ring
    __shared__ float4 e4buf[16];            // state ring, 16-deep

    if (h == 0) __builtin_amdgcn_s_setprio(1);   // R23-proven safe/neutral

    const float tx0 = uniformf(target_pos[0]), ty0 = uniformf(target_pos[1]);
    const float tx1 = uniformf(target_pos[2]), ty1 = uniformf(target_pos[3]);
    const float tx2 = uniformf(target_pos[4]), ty2 = uniformf(target_pos[5]);
    const float is0 = uniformf(1.0f / expf(logsigma[0]));
    const float is1 = uniformf(1.0f / expf(logsigma[1]));
    const float is2 = uniformf(1.0f / expf(logsigma[2]));

    // Paired weights for ages 16h..16h+15, rows A and B: 64 v2f pinned.
    v2f WxyA[16], WzcA[16], WxyB[16], WzcB[16];
    {
        const float* baseA = pw + rowA * 128;
        const float* baseB = pw + rowB * 128;
        #pragma unroll
        for (int i = 0; i < 16; ++i) {
            WxyA[i] = opaque_load8(baseA + 32 * h + 2 * i);
            WzcA[i] = opaque_load8(baseA + 64 + 32 * h + 2 * i);
            WxyB[i] = opaque_load8(baseB + 32 * h + 2 * i);
            WzcB[i] = opaque_load8(baseB + 64 + 32 * h + 2 * i);
        }
    }
    const float b1A = b1[rowA], b1B = b1[rowB];
    const float w20A = W2[rowA], w20B = W2[rowB];
    const float w21A = W2[HIDDEN + rowA], w21B = W2[HIDDEN + rowB];
    const float b2x = uniformf(b2[0]), b2y = uniformf(b2[1]);

    auto conc = [&](float px, float py) {
        float dx0 = px - tx0, dy0 = py - ty0;
        float dx1 = px - tx1, dy1 = py - ty1;
        float dx2 = px - tx2, dy2 = py - ty2;
        float cc  = is0 * __expf(-(dx0*dx0 + dy0*dy0) * is0);
        cc       += is1 * __expf(-(dx1*dx1 + dy1*dy1) * is1);
        cc       += is2 * __expf(-(dx2*dx2 + dy2*dy2) * is2);
        return cc;
    };

    float x  = uniformf(x_inits[3 * agent]);
    float y  = uniformf(x_inits[3 * agent + 1]);
    float th = uniformf(x_inits[3 * agent + 2]);
    float c  = conc(x, y);

    if (h == 0) {
        // ---------------- consumer wave ----------------
        v2f RA[16], RB[16];
        {   // seed slot s: sum_{k=s..15} W[k]·e(0)
            v2f exy0 = {x, y}, ezc0 = {th, c};
            v2f aA = {0.f,0.f}, aB = {0.f,0.f};
            #pragma unroll
            for (int k = 15; k >= 0; --k) {
                aA = WxyA[k]*exy0 + aA;  aA = WzcA[k]*ezc0 + aA;
                aB = WxyB[k]*exy0 + aB;  aB = WzcB[k]*ezc0 + aB;
                RA[k] = aA;  RB[k] = aB;
            }
            if (lane == 0) {
                float4 e0 = make_float4(x, y, th, c);
                #pragma unroll
                for (int m = 9; m < 16; ++m) e4buf[m] = e0;
                e4buf[0] = e0;
            }
        }
        // R33: sin/cos pipeline seed — values for step 0.
        float sn = __sinf(th), cs = __cosf(th);
        __syncthreads();              // seed barrier (both waves)
        float2 p0 = part1[0][lane];   // pl for step 0
        float2 p1, p2, p3;            // prefetch pipeline (filled after B0)
        v2f es_xy[4], es_zc[4];
        float S_c = 0.f, S_u = 0.f;

        auto h0_step = [&](int j, int s16, bool rd) {
            float hA = fmaxf((RA[j].x + RA[j].y) + p0.x + b1A, 0.f);
            float hB = fmaxf((RB[j].x + RB[j].y) + p0.y + b1B, 0.f);
            // R24: no slot zeroing -- batch (i==3,kk>=12) tap overwrites.
            float r0 = fmaf(w20A, hA, w20B * hB);
            float r1 = fmaf(w21A, hA, w21B * hB);
            wave_sum2_dpp(r0, r1);    // R25: fused dual reduction
            float s0 = __builtin_bit_cast(float,
                __builtin_amdgcn_readlane(__builtin_bit_cast(int, r0), 63));
            float s1 = __builtin_bit_cast(float,
                __builtin_amdgcn_readlane(__builtin_bit_cast(int, r1), 63));
            float v  = tanh_fast(s0 + b2x);
            float wv = tanh_fast(s1 + b2y);
            S_u += v * v + wv * wv;
            // R33: pipelined sn/cs (from prev step's th -- identical bits).
            float dv = DT * v;
            x  = fmaf(dv, cs, x);
            y  = fmaf(dv, sn, y);
            th = fmaf(DT, wv, th);
            sn = __sinf(th);  cs = __cosf(th);   // for step j+1, off-cycle
            c  = conc(x, y);
            S_c += c;
            // R34: e4buf write moved to per-group batch (see h0_flush)
            v2f exy = {x, y}, ezc = {th, c};
            es_xy[j & 3] = exy;  es_zc[j & 3] = ezc;
            // urgent taps: k <= 2 - (j&3)
            #pragma unroll
            for (int k = 0; k < 3; ++k) {
                if (k <= 2 - (j & 3)) {
                    const int m = (j + 1 + k) & 15;
                    RA[m] = WxyA[k]*exy + RA[m];  RA[m] = WzcA[k]*ezc + RA[m];
                    RB[m] = WxyB[k]*exy + RB[m];  RB[m] = WzcB[k]*ezc + RB[m];
                }
            }
            // R28: rotate prefetch pipeline; read 4 ahead when published
            p0 = p1;  p1 = p2;  p2 = p3;
            if (rd) p3 = part1[(s16 + j + 4) & 31][lane];
        };
        // R34: batched state publication — slots 4g+1..4g+4 from es bufs.
        auto h0_flush = [&](int g) {
            if (lane == 0) {
                #pragma unroll
                for (int i = 0; i < 4; ++i) {
                    e4buf[(4*g + 1 + i) & 15] =
                        make_float4(es_xy[i].x, es_xy[i].y,
                                    es_zc[i].x, es_zc[i].y);
                }
            }
        };
        auto h0_batch = [&](int q) {   // lazy taps of states e(.+4q+1..+4)
            #pragma unroll
            for (int kk = 0; kk < 16; ++kk) {
                #pragma unroll
                for (int i = 0; i < 4; ++i) {
                    if (kk >= 3 - i) {
                        const int m = (4*q + i + 1 + kk) & 15;
                        if (i == 3 && kk >= 12) {
                            // first write since consume -> overwrite
                            RA[m] = WxyA[kk]*es_xy[i];
                            RA[m] = WzcA[kk]*es_zc[i] + RA[m];
                            RB[m] = WxyB[kk]*es_xy[i];
                            RB[m] = WzcB[kk]*es_zc[i] + RB[m];
                        } else {
                            RA[m] = WxyA[kk]*es_xy[i] + RA[m];
                            RA[m] = WzcA[kk]*es_zc[i] + RA[m];
                            RB[m] = WxyB[kk]*es_xy[i] + RB[m];
                            RB[m] = WzcB[kk]*es_zc[i] + RB[m];
                        }
                    }
                }
            }
        };

        #pragma unroll 1
        for (int b = 0; b < 62; ++b) {
            const int s16 = (b & 1) << 4;
            __syncthreads();                       // B0
            p1 = part1[(s16 + 1) & 31][lane];      // rel 1..3: published
            p2 = part1[(s16 + 2) & 31][lane];      // in window b-1 (or seed)
            p3 = part1[(s16 + 3) & 31][lane];
            h0_step(0, s16, true);  h0_step(1, s16, true);
            h0_step(2, s16, true);  h0_step(3, s16, true);
            h0_flush(0);                           // slots 1..4 (read after B1)
            h0_batch(0);
            h0_step(4, s16, true);  h0_step(5, s16, false);
            h0_step(6, s16, false); h0_step(7, s16, false);
            h0_flush(1);                           // slots 5..8 (read after B1)
            h0_batch(1);
            __syncthreads();                       // B1
            p1 = part1[(s16 + 9) & 31][lane];      // rel 9..11: published
            p2 = part1[(s16 + 10) & 31][lane];     // by batches 0,1 -> B1
            p3 = part1[(s16 + 11) & 31][lane];
            h0_step(8, s16, true);   h0_step(9, s16, true);
            h0_step(10, s16, true);  h0_step(11, s16, true);
            h0_flush(2);                           // slots 9..12 (next B0)
            h0_batch(2);
            h0_step(12, s16, true);  h0_step(13, s16, false);
            h0_step(14, s16, false); h0_step(15, s16, false);
            h0_flush(3);                           // slots 13,14,15,0 (next B0)
            h0_batch(3);
        }
        // remainder: steps 992..999 (b=62, s16=0); pl up to abs 1000
        // shipped by window 61 batch3 -> published at B0. e4buf flushes
        // kept for shape-parity (values never read after kernel end).
        __syncthreads();
        p1 = part1[1][lane];
        p2 = part1[2][lane];
        p3 = part1[3][lane];
        h0_step(0, 0, true);  h0_step(1, 0, true);
        h0_step(2, 0, true);  h0_step(3, 0, true);
        h0_flush(0);
        h0_batch(0);
        h0_step(4, 0, true);  h0_step(5, 0, false);
        h0_step(6, 0, false); h0_step(7, 0, false);

        if (lane == 0) ws[agent] = make_float2(S_c, S_u);
    } else {
        // ---------------- producer wave (R27: overwrite-first) ----------
        v2f PA[20], PB[20];
        {   // ring seed: PA[idx] = sum_{k=idx+1..15} W[k]·e(0), idx 0..14
            v2f exy0 = {x, y}, ezc0 = {th, c};
            #pragma unroll
            for (int i = 15; i < 20; ++i) { PA[i] = (v2f){0.f,0.f}; PB[i] = (v2f){0.f,0.f}; }
            v2f aA = {0.f,0.f}, aB = {0.f,0.f};
            #pragma unroll
            for (int k = 15; k >= 1; --k) {
                aA = WxyA[k]*exy0 + aA;  aA = WzcA[k]*ezc0 + aA;
                aB = WxyB[k]*exy0 + aB;  aB = WzcB[k]*ezc0 + aB;
                PA[k-1] = aA;  PB[k-1] = aB;
            }
            // part1 prefill s=0..8: full 16-tap sum
            v2f fA = WxyA[0]*exy0 + aA;  fA = WzcA[0]*ezc0 + fA;
            v2f fB = WxyB[0]*exy0 + aB;  fB = WzcB[0]*ezc0 + fB;
            float2 full = make_float2(fA.x + fA.y, fB.x + fB.y);
            #pragma unroll
            for (int s = 0; s <= 8; ++s) part1[s][lane] = full;
        }
        __syncthreads();              // seed barrier

        auto h1_batch = [&](int n, int b1w) {
            // read 4 states e(16b-7+4n .. +3 more): e4buf[(9+4n+i)&15]
            v2f pxy[4], pzc[4];
            #pragma unroll
            for (int i = 0; i < 4; ++i) {
                float4 e = e4buf[(9 + 4*n + i) & 15];
                pxy[i] = (v2f){e.x, e.y};
                pzc[i] = (v2f){e.z, e.w};
            }
            // k-outer push; (i==3,kk>=12) = first writers of recycled
            // slots 15..18 -> overwrite (replaces tail zeroing).
            #pragma unroll
            for (int kk = 0; kk < 16; ++kk) {
                #pragma unroll
                for (int i = 0; i < 4; ++i) {
                    const int idx = i + kk;
                    if (i == 3 && kk >= 12) {
                        PA[idx] = WxyA[kk]*pxy[i];
                        PA[idx] = WzcA[kk]*pzc[i] + PA[idx];
                        PB[idx] = WxyB[kk]*pxy[i];
                        PB[idx] = WzcB[kk]*pzc[i] + PB[idx];
                    } else {
                        PA[idx] = WxyA[kk]*pxy[i] + PA[idx];
                        PA[idx] = WzcA[kk]*pzc[i] + PA[idx];
                        PB[idx] = WxyB[kk]*pxy[i] + PB[idx];
                        PB[idx] = WzcB[kk]*pzc[i] + PB[idx];
                    }
                }
            }
            // ship 4 completed partials: s = 16b + 9+4n + i
            #pragma unroll
            for (int i = 0; i < 4; ++i) {
                part1[(b1w * 16 + 9 + 4*n + i) & 31][lane] =
                    make_float2(PA[i].x + PA[i].y, PB[i].x + PB[i].y);
            }
            // rotate by 4; no tail zeroing (overwrites handle 15..18;
            // PA[19]/PB[19] stay 0 forever).
            #pragma unroll
            for (int i = 0; i < 16; ++i) { PA[i] = PA[i+4]; PB[i] = PB[i+4]; }
        };

        #pragma unroll 1
        for (int b = 0; b < 62; ++b) {
            const int b1w = b & 1;
            __syncthreads();
            h1_batch(0, b1w);
            h1_batch(1, b1w);
            __syncthreads();
            h1_batch(2, b1w);
            h1_batch(3, b1w);
        }
        __syncthreads();   // remainder barrier (match h0); nothing to ship
    }
}

__global__ void reduce_kernel(const float2* __restrict__ ws,
                              float* __restrict__ out) {
    const int tid = threadIdx.x;  // 256 threads
    float sc = 0.f, su = 0.f;
    for (int i = tid; i < N_AGENTS; i += 256) {
        float2 v = ws[i];
        sc += v.x;
        su += v.y;
    }
    #pragma unroll
    for (int off = 32; off > 0; off >>= 1) {
        sc += __shfl_xor(sc, off);
        su += __shfl_xor(su, off);
    }
    __shared__ float2 partw[4];
    int wave = tid >> 6;
    if ((tid & 63) == 0) partw[wave] = make_float2(sc, su);
    __syncthreads();
    if (tid == 0) {
        float SC = partw[0].x + partw[1].x + partw[2].x + partw[3].x;
        float SU = partw[0].y + partw[1].y + partw[2].y + partw[3].y;
        const float invNT  = 1.0f / (float)(N_AGENTS * T_STEPS);
        const float invNT2 = 1.0f / (float)(N_AGENTS * T_STEPS * 2);
        out[0] = -SC * invNT + SU * invNT2;
    }
}

extern "C" void kernel_launch(void* const* d_in, const int* in_sizes, int n_in,
                              void* d_out, int out_size, void* d_ws, size_t ws_size,
                              hipStream_t stream) {
    const float* target_pos = (const float*)d_in[0];
    const float* logsigma   = (const float*)d_in[1];
    const float* x_inits    = (const float*)d_in[2];
    const float* W1         = (const float*)d_in[3];
    const float* b1         = (const float*)d_in[4];
    const float* W2         = (const float*)d_in[5];
    const float* b2         = (const float*)d_in[6];

    float*  pw   = (float*)d_ws;                          // 64 KB packed W1
    float2* sums = (float2*)((char*)d_ws + 64 * 1024);    // per-agent sums

    pack_kernel<<<HIDDEN, 32, 0, stream>>>(W1, pw);
    sim_kernel<<<N_AGENTS, 128, 0, stream>>>(target_pos, logsigma, x_inits,
                                             pw, b1, W2, b2, sums);
    reduce_kernel<<<1, 256, 0, stream>>>(sums, (float*)d_out);
}

// Round 16
// 619.035 us; speedup vs baseline: 4.4459x; 1.0107x over previous
//
#include <hip/hip_runtime.h>

#define T_STEPS 1000
#define DT 0.1f
#define HIDDEN 128
#define N_AGENTS 1024

typedef float v2f __attribute__((ext_vector_type(2)));

// tanh(x) = 1 - 2/(exp(2x)+1); exact at +/-inf, ~1e-7 rel error.
// R35: exp2-fused. __expf(2x) = v_mul(x,2) -> v_mul(.,log2e) -> v_exp.
// Fused: v_mul(x, 2*log2e) -> v_exp. BIT-IDENTICAL: both are a SINGLE
// rounding of the real 2*x*log2e (doubling is exact; 2C is C with
// exponent+1, exactly representable). One chain mul removed per tanh.
__device__ __forceinline__ float tanh_fast(float x) {
    float e = __builtin_amdgcn_exp2f(x * 0x1.715476p+1f);  // 2*log2(e)
    return 1.0f - 2.0f * __builtin_amdgcn_rcpf(e + 1.0f);
}

// Opaque 8B load (R13-R18 proven residency mechanism).
__device__ __forceinline__ v2f opaque_load8(const float* p) {
    v2f v;
    asm volatile("global_load_dwordx2 %0, %1, off\n\ts_waitcnt vmcnt(0)"
                 : "=v"(v)
                 : "v"((unsigned long long)(uintptr_t)p)
                 : "memory");
    return v;
}

__device__ __forceinline__ float uniformf(float v) {
    return __builtin_bit_cast(float,
        __builtin_amdgcn_readfirstlane(__builtin_bit_cast(int, v)));
}

// R25: DUAL fused DPP reduction (bitwise-identical adds, 1 instr/stage,
// interleaved chains cover VALU->DPP wait states). Proven -2.9%.
// Volatile form (R29 A/B: non-volatile neutral-to-worse).
__device__ __forceinline__ void wave_sum2_dpp(float& a, float& b) {
    asm volatile(
        "s_nop 1\n\t"
        "v_add_f32_dpp %0, %0, %0 row_shr:1 row_mask:0xf bank_mask:0xf bound_ctrl:0\n\t"
        "v_add_f32_dpp %1, %1, %1 row_shr:1 row_mask:0xf bank_mask:0xf bound_ctrl:0\n\t"
        "s_nop 0\n\t"
        "v_add_f32_dpp %0, %0, %0 row_shr:2 row_mask:0xf bank_mask:0xf bound_ctrl:0\n\t"
        "v_add_f32_dpp %1, %1, %1 row_shr:2 row_mask:0xf bank_mask:0xf bound_ctrl:0\n\t"
        "s_nop 0\n\t"
        "v_add_f32_dpp %0, %0, %0 row_shr:4 row_mask:0xf bank_mask:0xf bound_ctrl:0\n\t"
        "v_add_f32_dpp %1, %1, %1 row_shr:4 row_mask:0xf bank_mask:0xf bound_ctrl:0\n\t"
        "s_nop 0\n\t"
        "v_add_f32_dpp %0, %0, %0 row_shr:8 row_mask:0xf bank_mask:0xf bound_ctrl:0\n\t"
        "v_add_f32_dpp %1, %1, %1 row_shr:8 row_mask:0xf bank_mask:0xf bound_ctrl:0\n\t"
        "s_nop 0\n\t"
        "v_add_f32_dpp %0, %0, %0 row_bcast:15 row_mask:0xa bank_mask:0xf bound_ctrl:0\n\t"
        "v_add_f32_dpp %1, %1, %1 row_bcast:15 row_mask:0xa bank_mask:0xf bound_ctrl:0\n\t"
        "s_nop 0\n\t"
        "v_add_f32_dpp %0, %0, %0 row_bcast:31 row_mask:0xc bank_mask:0xf bound_ctrl:0\n\t"
        "v_add_f32_dpp %1, %1, %1 row_bcast:31 row_mask:0xc bank_mask:0xf bound_ctrl:0\n\t"
        "s_nop 1"
        : "+v"(a), "+v"(b));
}

// Pre-pack W1 into component-paired layout (R14-R18 verified).
__global__ void pack_kernel(const float* __restrict__ W1,
                            float* __restrict__ pw) {
    const int row = blockIdx.x;     // 128
    const int a   = threadIdx.x;    // 32
    const float* rp = W1 + row * 128;
    float* out = pw + row * 128;
    out[2*a]          = rp[3*a];
    out[2*a + 1]      = rp[3*a + 1];
    out[64 + 2*a]     = rp[3*a + 2];
    out[64 + 2*a + 1] = rp[96 + a];
}

// R35 = R34 (625.7us anchor, absmax 0.0) + ONE delta: exp2-fused tanh
// (see tanh_fast). Everything else byte-identical to R34.
__global__ __launch_bounds__(128)
__attribute__((amdgpu_waves_per_eu(2, 2)))
void sim_kernel(const float* __restrict__ target_pos,
                const float* __restrict__ logsigma,
                const float* __restrict__ x_inits,
                const float* __restrict__ pw,
                const float* __restrict__ b1,
                const float* __restrict__ W2,
                const float* __restrict__ b2,
                float2* __restrict__ ws) {
    const int agent = blockIdx.x;
    const int tid  = threadIdx.x;   // 0..127
    const int h    = tid >> 6;      // 0 = consumer, 1 = producer
    const int lane = tid & 63;
    const int rowA = lane;
    const int rowB = lane + 64;

    __shared__ float2 part1[32][64];        // h=1 -> h=0 partial ring
    __shared__ float4 e4buf[16];            // state ring, 16-deep

    if (h == 0) __builtin_amdgcn_s_setprio(1);   // R23-proven safe/neutral

    const float tx0 = uniformf(target_pos[0]), ty0 = uniformf(target_pos[1]);
    const float tx1 = uniformf(target_pos[2]), ty1 = uniformf(target_pos[3]);
    const float tx2 = uniformf(target_pos[4]), ty2 = uniformf(target_pos[5]);
    const float is0 = uniformf(1.0f / expf(logsigma[0]));
    const float is1 = uniformf(1.0f / expf(logsigma[1]));
    const float is2 = uniformf(1.0f / expf(logsigma[2]));

    // Paired weights for ages 16h..16h+15, rows A and B: 64 v2f pinned.
    v2f WxyA[16], WzcA[16], WxyB[16], WzcB[16];
    {
        const float* baseA = pw + rowA * 128;
        const float* baseB = pw + rowB * 128;
        #pragma unroll
        for (int i = 0; i < 16; ++i) {
            WxyA[i] = opaque_load8(baseA + 32 * h + 2 * i);
            WzcA[i] = opaque_load8(baseA + 64 + 32 * h + 2 * i);
            WxyB[i] = opaque_load8(baseB + 32 * h + 2 * i);
            WzcB[i] = opaque_load8(baseB + 64 + 32 * h + 2 * i);
        }
    }
    const float b1A = b1[rowA], b1B = b1[rowB];
    const float w20A = W2[rowA], w20B = W2[rowB];
    const float w21A = W2[HIDDEN + rowA], w21B = W2[HIDDEN + rowB];
    const float b2x = uniformf(b2[0]), b2y = uniformf(b2[1]);

    auto conc = [&](float px, float py) {
        float dx0 = px - tx0, dy0 = py - ty0;
        float dx1 = px - tx1, dy1 = py - ty1;
        float dx2 = px - tx2, dy2 = py - ty2;
        float cc  = is0 * __expf(-(dx0*dx0 + dy0*dy0) * is0);
        cc       += is1 * __expf(-(dx1*dx1 + dy1*dy1) * is1);
        cc       += is2 * __expf(-(dx2*dx2 + dy2*dy2) * is2);
        return cc;
    };

    float x  = uniformf(x_inits[3 * agent]);
    float y  = uniformf(x_inits[3 * agent + 1]);
    float th = uniformf(x_inits[3 * agent + 2]);
    float c  = conc(x, y);

    if (h == 0) {
        // ---------------- consumer wave ----------------
        v2f RA[16], RB[16];
        {   // seed slot s: sum_{k=s..15} W[k]·e(0)
            v2f exy0 = {x, y}, ezc0 = {th, c};
            v2f aA = {0.f,0.f}, aB = {0.f,0.f};
            #pragma unroll
            for (int k = 15; k >= 0; --k) {
                aA = WxyA[k]*exy0 + aA;  aA = WzcA[k]*ezc0 + aA;
                aB = WxyB[k]*exy0 + aB;  aB = WzcB[k]*ezc0 + aB;
                RA[k] = aA;  RB[k] = aB;
            }
            if (lane == 0) {
                float4 e0 = make_float4(x, y, th, c);
                #pragma unroll
                for (int m = 9; m < 16; ++m) e4buf[m] = e0;
                e4buf[0] = e0;
            }
        }
        // R33: sin/cos pipeline seed — values for step 0.
        float sn = __sinf(th), cs = __cosf(th);
        __syncthreads();              // seed barrier (both waves)
        float2 p0 = part1[0][lane];   // pl for step 0
        float2 p1, p2, p3;            // prefetch pipeline (filled after B0)
        v2f es_xy[4], es_zc[4];
        float S_c = 0.f, S_u = 0.f;

        auto h0_step = [&](int j, int s16, bool rd) {
            float hA = fmaxf((RA[j].x + RA[j].y) + p0.x + b1A, 0.f);
            float hB = fmaxf((RB[j].x + RB[j].y) + p0.y + b1B, 0.f);
            // R24: no slot zeroing -- batch (i==3,kk>=12) tap overwrites.
            float r0 = fmaf(w20A, hA, w20B * hB);
            float r1 = fmaf(w21A, hA, w21B * hB);
            wave_sum2_dpp(r0, r1);    // R25: fused dual reduction
            float s0 = __builtin_bit_cast(float,
                __builtin_amdgcn_readlane(__builtin_bit_cast(int, r0), 63));
            float s1 = __builtin_bit_cast(float,
                __builtin_amdgcn_readlane(__builtin_bit_cast(int, r1), 63));
            float v  = tanh_fast(s0 + b2x);
            float wv = tanh_fast(s1 + b2y);
            S_u += v * v + wv * wv;
            // R33: pipelined sn/cs (from prev step's th -- identical bits).
            float dv = DT * v;
            x  = fmaf(dv, cs, x);
            y  = fmaf(dv, sn, y);
            th = fmaf(DT, wv, th);
            sn = __sinf(th);  cs = __cosf(th);   // for step j+1, off-cycle
            c  = conc(x, y);
            S_c += c;
            // R34: e4buf write moved to per-group batch (see h0_flush)
            v2f exy = {x, y}, ezc = {th, c};
            es_xy[j & 3] = exy;  es_zc[j & 3] = ezc;
            // urgent taps: k <= 2 - (j&3)
            #pragma unroll
            for (int k = 0; k < 3; ++k) {
                if (k <= 2 - (j & 3)) {
                    const int m = (j + 1 + k) & 15;
                    RA[m] = WxyA[k]*exy + RA[m];  RA[m] = WzcA[k]*ezc + RA[m];
                    RB[m] = WxyB[k]*exy + RB[m];  RB[m] = WzcB[k]*ezc + RB[m];
                }
            }
            // R28: rotate prefetch pipeline; read 4 ahead when published
            p0 = p1;  p1 = p2;  p2 = p3;
            if (rd) p3 = part1[(s16 + j + 4) & 31][lane];
        };
        // R34: batched state publication — slots 4g+1..4g+4 from es bufs.
        auto h0_flush = [&](int g) {
            if (lane == 0) {
                #pragma unroll
                for (int i = 0; i < 4; ++i) {
                    e4buf[(4*g + 1 + i) & 15] =
                        make_float4(es_xy[i].x, es_xy[i].y,
                                    es_zc[i].x, es_zc[i].y);
                }
            }
        };
        auto h0_batch = [&](int q) {   // lazy taps of states e(.+4q+1..+4)
            #pragma unroll
            for (int kk = 0; kk < 16; ++kk) {
                #pragma unroll
                for (int i = 0; i < 4; ++i) {
                    if (kk >= 3 - i) {
                        const int m = (4*q + i + 1 + kk) & 15;
                        if (i == 3 && kk >= 12) {
                            // first write since consume -> overwrite
                            RA[m] = WxyA[kk]*es_xy[i];
                            RA[m] = WzcA[kk]*es_zc[i] + RA[m];
                            RB[m] = WxyB[kk]*es_xy[i];
                            RB[m] = WzcB[kk]*es_zc[i] + RB[m];
                        } else {
                            RA[m] = WxyA[kk]*es_xy[i] + RA[m];
                            RA[m] = WzcA[kk]*es_zc[i] + RA[m];
                            RB[m] = WxyB[kk]*es_xy[i] + RB[m];
                            RB[m] = WzcB[kk]*es_zc[i] + RB[m];
                        }
                    }
                }
            }
        };

        #pragma unroll 1
        for (int b = 0; b < 62; ++b) {
            const int s16 = (b & 1) << 4;
            __syncthreads();                       // B0
            p1 = part1[(s16 + 1) & 31][lane];      // rel 1..3: published
            p2 = part1[(s16 + 2) & 31][lane];      // in window b-1 (or seed)
            p3 = part1[(s16 + 3) & 31][lane];
            h0_step(0, s16, true);  h0_step(1, s16, true);
            h0_step(2, s16, true);  h0_step(3, s16, true);
            h0_flush(0);                           // slots 1..4 (read after B1)
            h0_batch(0);
            h0_step(4, s16, true);  h0_step(5, s16, false);
            h0_step(6, s16, false); h0_step(7, s16, false);
            h0_flush(1);                           // slots 5..8 (read after B1)
            h0_batch(1);
            __syncthreads();                       // B1
            p1 = part1[(s16 + 9) & 31][lane];      // rel 9..11: published
            p2 = part1[(s16 + 10) & 31][lane];     // by batches 0,1 -> B1
            p3 = part1[(s16 + 11) & 31][lane];
            h0_step(8, s16, true);   h0_step(9, s16, true);
            h0_step(10, s16, true);  h0_step(11, s16, true);
            h0_flush(2);                           // slots 9..12 (next B0)
            h0_batch(2);
            h0_step(12, s16, true);  h0_step(13, s16, false);
            h0_step(14, s16, false); h0_step(15, s16, false);
            h0_flush(3);                           // slots 13,14,15,0 (next B0)
            h0_batch(3);
        }
        // remainder: steps 992..999 (b=62, s16=0); pl up to abs 1000
        // shipped by window 61 batch3 -> published at B0.
        __syncthreads();
        p1 = part1[1][lane];
        p2 = part1[2][lane];
        p3 = part1[3][lane];
        h0_step(0, 0, true);  h0_step(1, 0, true);
        h0_step(2, 0, true);  h0_step(3, 0, true);
        h0_flush(0);
        h0_batch(0);
        h0_step(4, 0, true);  h0_step(5, 0, false);
        h0_step(6, 0, false); h0_step(7, 0, false);

        if (lane == 0) ws[agent] = make_float2(S_c, S_u);
    } else {
        // ---------------- producer wave (R27: overwrite-first) ----------
        v2f PA[20], PB[20];
        {   // ring seed: PA[idx] = sum_{k=idx+1..15} W[k]·e(0), idx 0..14
            v2f exy0 = {x, y}, ezc0 = {th, c};
            #pragma unroll
            for (int i = 15; i < 20; ++i) { PA[i] = (v2f){0.f,0.f}; PB[i] = (v2f){0.f,0.f}; }
            v2f aA = {0.f,0.f}, aB = {0.f,0.f};
            #pragma unroll
            for (int k = 15; k >= 1; --k) {
                aA = WxyA[k]*exy0 + aA;  aA = WzcA[k]*ezc0 + aA;
                aB = WxyB[k]*exy0 + aB;  aB = WzcB[k]*ezc0 + aB;
                PA[k-1] = aA;  PB[k-1] = aB;
            }
            // part1 prefill s=0..8: full 16-tap sum
            v2f fA = WxyA[0]*exy0 + aA;  fA = WzcA[0]*ezc0 + fA;
            v2f fB = WxyB[0]*exy0 + aB;  fB = WzcB[0]*ezc0 + fB;
            float2 full = make_float2(fA.x + fA.y, fB.x + fB.y);
            #pragma unroll
            for (int s = 0; s <= 8; ++s) part1[s][lane] = full;
        }
        __syncthreads();              // seed barrier

        auto h1_batch = [&](int n, int b1w) {
            // read 4 states e(16b-7+4n .. +3 more): e4buf[(9+4n+i)&15]
            v2f pxy[4], pzc[4];
            #pragma unroll
            for (int i = 0; i < 4; ++i) {
                float4 e = e4buf[(9 + 4*n + i) & 15];
                pxy[i] = (v2f){e.x, e.y};
                pzc[i] = (v2f){e.z, e.w};
            }
            // k-outer push; (i==3,kk>=12) = first writers of recycled
            // slots 15..18 -> overwrite (replaces tail zeroing).
            #pragma unroll
            for (int kk = 0; kk < 16; ++kk) {
                #pragma unroll
                for (int i = 0; i < 4; ++i) {
                    const int idx = i + kk;
                    if (i == 3 && kk >= 12) {
                        PA[idx] = WxyA[kk]*pxy[i];
                        PA[idx] = WzcA[kk]*pzc[i] + PA[idx];
                        PB[idx] = WxyB[kk]*pxy[i];
                        PB[idx] = WzcB[kk]*pzc[i] + PB[idx];
                    } else {
                        PA[idx] = WxyA[kk]*pxy[i] + PA[idx];
                        PA[idx] = WzcA[kk]*pzc[i] + PA[idx];
                        PB[idx] = WxyB[kk]*pxy[i] + PB[idx];
                        PB[idx] = WzcB[kk]*pzc[i] + PB[idx];
                    }
                }
            }
            // ship 4 completed partials: s = 16b + 9+4n + i
            #pragma unroll
            for (int i = 0; i < 4; ++i) {
                part1[(b1w * 16 + 9 + 4*n + i) & 31][lane] =
                    make_float2(PA[i].x + PA[i].y, PB[i].x + PB[i].y);
            }
            // rotate by 4; no tail zeroing (overwrites handle 15..18;
            // PA[19]/PB[19] stay 0 forever).
            #pragma unroll
            for (int i = 0; i < 16; ++i) { PA[i] = PA[i+4]; PB[i] = PB[i+4]; }
        };

        #pragma unroll 1
        for (int b = 0; b < 62; ++b) {
            const int b1w = b & 1;
            __syncthreads();
            h1_batch(0, b1w);
            h1_batch(1, b1w);
            __syncthreads();
            h1_batch(2, b1w);
            h1_batch(3, b1w);
        }
        __syncthreads();   // remainder barrier (match h0); nothing to ship
    }
}

__global__ void reduce_kernel(const float2* __restrict__ ws,
                              float* __restrict__ out) {
    const int tid = threadIdx.x;  // 256 threads
    float sc = 0.f, su = 0.f;
    for (int i = tid; i < N_AGENTS; i += 256) {
        float2 v = ws[i];
        sc += v.x;
        su += v.y;
    }
    #pragma unroll
    for (int off = 32; off > 0; off >>= 1) {
        sc += __shfl_xor(sc, off);
        su += __shfl_xor(su, off);
    }
    __shared__ float2 partw[4];
    int wave = tid >> 6;
    if ((tid & 63) == 0) partw[wave] = make_float2(sc, su);
    __syncthreads();
    if (tid == 0) {
        float SC = partw[0].x + partw[1].x + partw[2].x + partw[3].x;
        float SU = partw[0].y + partw[1].y + partw[2].y + partw[3].y;
        const float invNT  = 1.0f / (float)(N_AGENTS * T_STEPS);
        const float invNT2 = 1.0f / (float)(N_AGENTS * T_STEPS * 2);
        out[0] = -SC * invNT + SU * invNT2;
    }
}

extern "C" void kernel_launch(void* const* d_in, const int* in_sizes, int n_in,
                              void* d_out, int out_size, void* d_ws, size_t ws_size,
                              hipStream_t stream) {
    const float* target_pos = (const float*)d_in[0];
    const float* logsigma   = (const float*)d_in[1];
    const float* x_inits    = (const float*)d_in[2];
    const float* W1         = (const float*)d_in[3];
    const float* b1         = (const float*)d_in[4];
    const float* W2         = (const float*)d_in[5];
    const float* b2         = (const float*)d_in[6];

    float*  pw   = (float*)d_ws;                          // 64 KB packed W1
    float2* sums = (float2*)((char*)d_ws + 64 * 1024);    // per-agent sums

    pack_kernel<<<HIDDEN, 32, 0, stream>>>(W1, pw);
    sim_kernel<<<N_AGENTS, 128, 0, stream>>>(target_pos, logsigma, x_inits,
                                             pw, b1, W2, b2, sums);
    reduce_kernel<<<1, 256, 0, stream>>>(sums, (float*)d_out);
}